// Round 1
// baseline (596.741 us; speedup 1.0000x reference)
//
#include <hip/hip_runtime.h>
#include <hip/hip_bf16.h>
#include <stdint.h>

typedef __bf16 bf16_t;
typedef __bf16 bf16x8 __attribute__((ext_vector_type(8)));
typedef float  f32x4  __attribute__((ext_vector_type(4)));

#define MFMA(a, b, c) __builtin_amdgcn_mfma_f32_16x16x32_bf16((a), (b), (c), 0, 0, 0)

// ---------------------------------------------------------------- K1: linears
// ui[bl][p] = sum_i h[bl][i]*Wi[p][i] + bi[p]  (and vj with Wj,bj), bf16 out
__global__ __launch_bounds__(128) void k_linear(
    const float* __restrict__ h, const float* __restrict__ Wi,
    const float* __restrict__ bi, const float* __restrict__ Wj,
    const float* __restrict__ bj, bf16_t* __restrict__ ui,
    bf16_t* __restrict__ vj) {
  int bl = blockIdx.x;
  int which = blockIdx.y;
  const float* W = which ? Wj : Wi;
  const float* bias = which ? bj : bi;
  bf16_t* out = which ? vj : ui;
  __shared__ float hrow[1024];
  for (int i = threadIdx.x; i < 1024; i += 128) hrow[i] = h[bl * 1024 + i];
  __syncthreads();
  int p = threadIdx.x;
  const float* w = W + (size_t)p * 1024;
  float acc = bias[p];
  for (int i = 0; i < 1024; i += 4) {
    f32x4 wv = *(const f32x4*)(w + i);
    acc += hrow[i] * wv[0] + hrow[i + 1] * wv[1] + hrow[i + 2] * wv[2] +
           hrow[i + 3] * wv[3];
  }
  out[bl * 128 + p] = (bf16_t)acc;
}

// ------------------------------------------------- K2a: W[i][j][k]->Wt[k][j][i]
__global__ __launch_bounds__(256) void k_wt(const float* __restrict__ W,
                                            bf16_t* __restrict__ Wt) {
  int j = blockIdx.x;
  int i0 = blockIdx.y * 32, k0 = blockIdx.z * 32;
  __shared__ float tile[32][33];
  int tx = threadIdx.x & 31, ty = threadIdx.x >> 5;  // ty 0..7
#pragma unroll
  for (int r = 0; r < 4; r++) {
    int ii = ty + r * 8;
    tile[ii][tx] = W[(size_t)(i0 + ii) * 16384 + j * 128 + (k0 + tx)];
  }
  __syncthreads();
#pragma unroll
  for (int r = 0; r < 4; r++) {
    int kk = ty + r * 8;
    Wt[(size_t)(k0 + kk) * 16384 + j * 128 + (i0 + tx)] = (bf16_t)tile[tx][kk];
  }
}

// ------------------------------- K2b: mix_w[oc][ic][tap] -> Wc[tap][oc][ic] bf16
__global__ __launch_bounds__(256) void k_wc(const float* __restrict__ mw,
                                            bf16_t* __restrict__ Wc) {
  int idx = blockIdx.x * 256 + threadIdx.x;
  if (idx < 147456) {
    int ic = idx & 127, oc = (idx >> 7) & 127, tap = idx >> 14;
    Wc[idx] = (bf16_t)mw[oc * 1152 + ic * 9 + tap];
  }
}

// --------------------------------------------- K2c: out_w -> bf16 (already [oc2][mc])
__global__ __launch_bounds__(256) void k_wo(const float* __restrict__ ow,
                                            bf16_t* __restrict__ Wo) {
  int idx = blockIdx.x * 256 + threadIdx.x;
  if (idx < 16384) Wo[idx] = (bf16_t)ow[idx];
}

// ------------------- K3: t[bl][k*128+j] = sum_i ui[bl][i] * Wt[k][j][i]  (GEMM)
__global__ __launch_bounds__(256) void k_tgemm(const bf16_t* __restrict__ A,
                                               const bf16_t* __restrict__ Bt,
                                               bf16_t* __restrict__ T) {
  int m0 = blockIdx.x * 64;  // bl
  int n0 = blockIdx.y * 64;  // (k,j)
  __shared__ bf16_t Al[64][136], Bl[64][136];
  for (int c = threadIdx.x; c < 64 * 16; c += 256) {
    int row = c >> 4, col = (c & 15) * 8;
    *(uint4*)&Al[row][col] = *(const uint4*)&A[(size_t)(m0 + row) * 128 + col];
    *(uint4*)&Bl[row][col] = *(const uint4*)&Bt[(size_t)(n0 + row) * 128 + col];
  }
  __syncthreads();
  int w = threadIdx.x >> 6, ln = threadIdx.x & 63;
  int wr = (w >> 1) * 32, wc = (w & 1) * 32;
  int lr = ln & 15, hi8 = (ln >> 4) * 8, rb = (ln >> 4) * 4;
  f32x4 acc[2][2] = {};
#pragma unroll
  for (int kc = 0; kc < 128; kc += 32) {
    bf16x8 a0 = *(bf16x8*)&Al[wr + lr][kc + hi8];
    bf16x8 a1 = *(bf16x8*)&Al[wr + 16 + lr][kc + hi8];
    bf16x8 b0 = *(bf16x8*)&Bl[wc + lr][kc + hi8];
    bf16x8 b1 = *(bf16x8*)&Bl[wc + 16 + lr][kc + hi8];
    acc[0][0] = MFMA(a0, b0, acc[0][0]);
    acc[0][1] = MFMA(a0, b1, acc[0][1]);
    acc[1][0] = MFMA(a1, b0, acc[1][0]);
    acc[1][1] = MFMA(a1, b1, acc[1][1]);
  }
#pragma unroll
  for (int fm = 0; fm < 2; fm++)
#pragma unroll
    for (int fn = 0; fn < 2; fn++) {
      int col = n0 + wc + fn * 16 + lr;
#pragma unroll
      for (int r = 0; r < 4; r++) {
        int row = m0 + wr + fm * 16 + rb + r;
        T[(size_t)row * 16384 + col] = (bf16_t)acc[fm][fn][r];
      }
    }
}

// ------- K4: feat[b][l][m][k] = sum_j t[bl][k][j] * vj[b][m][j]  (per-l GEMMs)
__global__ __launch_bounds__(256) void k_feat(const bf16_t* __restrict__ T,
                                              const bf16_t* __restrict__ Vb,
                                              bf16_t* __restrict__ F) {
  int bl = blockIdx.x;
  int b = bl / 384;
  __shared__ bf16_t Tl[128][136];
  __shared__ bf16_t Vm[64][136];
  const bf16_t* tsrc = T + (size_t)bl * 16384;
  for (int c = threadIdx.x; c < 128 * 16; c += 256) {
    int row = c >> 4, col = (c & 15) * 8;
    *(uint4*)&Tl[row][col] = *(const uint4*)&tsrc[row * 128 + col];
  }
  int w = threadIdx.x >> 6, ln = threadIdx.x & 63;
  int wr = (w >> 1) * 64, wc = (w & 1) * 32;
  int lr = ln & 15, hi8 = (ln >> 4) * 8, rb = (ln >> 4) * 4;
  size_t base = (size_t)bl * 384 * 128;
  for (int mt = 0; mt < 6; mt++) {
    __syncthreads();
    for (int c = threadIdx.x; c < 64 * 16; c += 256) {
      int row = c >> 4, col = (c & 15) * 8;
      *(uint4*)&Vm[row][col] =
          *(const uint4*)&Vb[(size_t)(b * 384 + mt * 64 + row) * 128 + col];
    }
    __syncthreads();
    f32x4 acc[4][2] = {};
#pragma unroll
    for (int kc = 0; kc < 128; kc += 32) {
      bf16x8 b0 = *(bf16x8*)&Vm[wc + lr][kc + hi8];
      bf16x8 b1 = *(bf16x8*)&Vm[wc + 16 + lr][kc + hi8];
#pragma unroll
      for (int fm = 0; fm < 4; fm++) {
        bf16x8 av = *(bf16x8*)&Tl[wr + fm * 16 + lr][kc + hi8];
        acc[fm][0] = MFMA(av, b0, acc[fm][0]);
        acc[fm][1] = MFMA(av, b1, acc[fm][1]);
      }
    }
    union {
      bf16_t h[4];
      uint2 u;
    } pk;
#pragma unroll
    for (int fm = 0; fm < 4; fm++)
#pragma unroll
      for (int fn = 0; fn < 2; fn++) {
        int m = mt * 64 + wc + fn * 16 + lr;
        int kb = wr + fm * 16 + rb;
#pragma unroll
        for (int r = 0; r < 4; r++) pk.h[r] = (bf16_t)acc[fm][fn][r];
        *(uint2*)&F[base + (size_t)m * 128 + kb] = pk.u;
      }
  }
}

// --------------------------- K5a: partial per-(b,k) sum/sumsq over pixel chunks
__global__ __launch_bounds__(256) void k_stats1(const bf16_t* __restrict__ F,
                                                float* __restrict__ part) {
  int b = blockIdx.y, ch = blockIdx.x;  // 512 chunks of 288 pixels
  int k = threadIdx.x & 127, half = threadIdx.x >> 7;
  size_t base = ((size_t)b * 147456 + ch * 288 + half * 144) * 128 + k;
  float s = 0.f, q = 0.f;
  for (int p = 0; p < 144; p++) {
    float v = (float)F[base + (size_t)p * 128];
    s += v;
    q += v * v;
  }
  __shared__ float red[512];
  red[threadIdx.x] = s;
  red[256 + threadIdx.x] = q;
  __syncthreads();
  if (half == 0) {
    part[(((size_t)b * 512 + ch) * 128 + k) * 2] = red[k] + red[128 + k];
    part[(((size_t)b * 512 + ch) * 128 + k) * 2 + 1] =
        red[256 + k] + red[384 + k];
  }
}

// ----------------------------------------- K5b: finalize scale/shift per (b,k)
__global__ __launch_bounds__(256) void k_stats2(const float* __restrict__ part,
                                                const float* __restrict__ gamma,
                                                const float* __restrict__ beta,
                                                float* __restrict__ ss) {
  int t = threadIdx.x;
  int b = t >> 7, k = t & 127;
  float s = 0.f, q = 0.f;
  for (int c = 0; c < 512; c++) {
    s += part[(((size_t)b * 512 + c) * 128 + k) * 2];
    q += part[(((size_t)b * 512 + c) * 128 + k) * 2 + 1];
  }
  const float inv = 1.0f / 147456.0f;
  float mean = s * inv;
  float var = q * inv - mean * mean;
  float sc = gamma[k] * rsqrtf(var + 1e-5f);
  ss[(b * 128 + k) * 2] = sc;
  ss[(b * 128 + k) * 2 + 1] = beta[k] - mean * sc;
}

// --- K7: fused norm+relu -> conv3x3 (implicit GEMM) -> relu -> conv1x1 + bias
__global__ __launch_bounds__(256) void k_conv(
    const bf16_t* __restrict__ F, const float* __restrict__ ss,
    const bf16_t* __restrict__ Wc, const bf16_t* __restrict__ Wo,
    const float* __restrict__ outb, float* __restrict__ out) {
  int xt = blockIdx.x, y = blockIdx.y, b = blockIdx.z;
  int x0 = xt * 64;
  __shared__ bf16_t Asl[128][40];
  __shared__ bf16_t Bsl[66][40];
  __shared__ bf16_t Mx[64][136];
  __shared__ float ssc[128], ssh[128];
  if (threadIdx.x < 128) {
    ssc[threadIdx.x] = ss[(b * 128 + threadIdx.x) * 2];
    ssh[threadIdx.x] = ss[(b * 128 + threadIdx.x) * 2 + 1];
  }
  int w = threadIdx.x >> 6, ln = threadIdx.x & 63;
  int wr = (w >> 1) * 64, wc4 = (w & 1) * 32;
  int lr = ln & 15, hi8 = (ln >> 4) * 8, rb = (ln >> 4) * 4;
  f32x4 acc[4][2] = {};
  for (int icc = 0; icc < 128; icc += 32) {
    for (int dy = 0; dy < 3; dy++) {
      int yy = y + dy - 1;
      bool yok = (yy >= 0 && yy < 384);
      for (int dx = 0; dx < 3; dx++) {
        __syncthreads();  // guard LDS reuse vs previous MFMA reads
        if (dx == 0) {
          // stage B slab [66 px][32 ic]: normalized+relu'd feat, zero-padded
          for (int idx = threadIdx.x; idx < 66 * 32; idx += 256) {
            int px = idx >> 5, ic = idx & 31;
            int xx = x0 - 1 + px;
            float v = 0.f;
            if (yok && xx >= 0 && xx < 384) {
              float f =
                  (float)F[((size_t)(b * 384 + yy) * 384 + xx) * 128 + icc + ic];
              v = f * ssc[icc + ic] + ssh[icc + ic];
              v = v > 0.f ? v : 0.f;
            }
            Bsl[px][ic] = (bf16_t)v;
          }
        }
        // stage A slab [128 oc][32 ic] for this tap
        for (int idx = threadIdx.x; idx < 128 * 32; idx += 256) {
          int oc = idx >> 5, ic = idx & 31;
          Asl[oc][ic] = Wc[(size_t)(dy * 3 + dx) * 16384 + oc * 128 + icc + ic];
        }
        __syncthreads();
        bf16x8 b0 = *(bf16x8*)&Bsl[wc4 + lr + dx][hi8];
        bf16x8 b1 = *(bf16x8*)&Bsl[wc4 + 16 + lr + dx][hi8];
#pragma unroll
        for (int fm = 0; fm < 4; fm++) {
          bf16x8 av = *(bf16x8*)&Asl[wr + fm * 16 + lr][hi8];
          acc[fm][0] = MFMA(av, b0, acc[fm][0]);
          acc[fm][1] = MFMA(av, b1, acc[fm][1]);
        }
      }
    }
  }
  // epilogue: relu(mix) -> Mx[px][mc] bf16, then 1x1 GEMM + bias
  __syncthreads();
  union {
    bf16_t h[4];
    uint2 u;
  } pk;
#pragma unroll
  for (int fm = 0; fm < 4; fm++)
#pragma unroll
    for (int fn = 0; fn < 2; fn++) {
      int px = wc4 + fn * 16 + lr;
      int mcb = wr + fm * 16 + rb;
#pragma unroll
      for (int r = 0; r < 4; r++) {
        float v = acc[fm][fn][r];
        pk.h[r] = (bf16_t)(v > 0.f ? v : 0.f);
      }
      *(uint2*)&Mx[px][mcb] = pk.u;
    }
  f32x4 acc2[4][2] = {};
  for (int kc = 0; kc < 128; kc += 32) {
    __syncthreads();
    for (int idx = threadIdx.x; idx < 128 * 32; idx += 256) {
      int oc = idx >> 5, ic = idx & 31;
      Asl[oc][ic] = Wo[oc * 128 + kc + ic];
    }
    __syncthreads();
    bf16x8 b0 = *(bf16x8*)&Mx[wc4 + lr][kc + hi8];
    bf16x8 b1 = *(bf16x8*)&Mx[wc4 + 16 + lr][kc + hi8];
#pragma unroll
    for (int fm = 0; fm < 4; fm++) {
      bf16x8 av = *(bf16x8*)&Asl[wr + fm * 16 + lr][hi8];
      acc2[fm][0] = MFMA(av, b0, acc2[fm][0]);
      acc2[fm][1] = MFMA(av, b1, acc2[fm][1]);
    }
  }
#pragma unroll
  for (int fm = 0; fm < 4; fm++)
#pragma unroll
    for (int fn = 0; fn < 2; fn++) {
      int x = x0 + wc4 + fn * 16 + lr;
#pragma unroll
      for (int r = 0; r < 4; r++) {
        int oc2 = wr + fm * 16 + rb + r;
        out[((size_t)(b * 128 + oc2) * 384 + y) * 384 + x] =
            acc2[fm][fn][r] + outb[oc2];
      }
    }
}

extern "C" void kernel_launch(void* const* d_in, const int* in_sizes, int n_in,
                              void* d_out, int out_size, void* d_ws,
                              size_t ws_size, hipStream_t stream) {
  const float* h = (const float*)d_in[0];
  const float* Wi = (const float*)d_in[1];
  const float* bi = (const float*)d_in[2];
  const float* Wj = (const float*)d_in[3];
  const float* bj = (const float*)d_in[4];
  const float* Wbl = (const float*)d_in[5];
  const float* gamma = (const float*)d_in[6];
  const float* beta = (const float*)d_in[7];
  const float* mw = (const float*)d_in[8];
  const float* ow = (const float*)d_in[9];
  const float* ob = (const float*)d_in[10];
  float* out = (float*)d_out;

  char* ws = (char*)d_ws;
  size_t off = 0;
  auto alloc = [&](size_t bytes) -> void* {
    void* p = ws + off;
    off = (off + bytes + 255) & ~(size_t)255;
    return p;
  };
  bf16_t* ui_b = (bf16_t*)alloc(768 * 128 * 2);
  bf16_t* vj_b = (bf16_t*)alloc(768 * 128 * 2);
  bf16_t* Wt = (bf16_t*)alloc((size_t)2097152 * 2);
  bf16_t* Wc = (bf16_t*)alloc((size_t)147456 * 2);
  bf16_t* Wo = (bf16_t*)alloc((size_t)16384 * 2);
  bf16_t* T = (bf16_t*)alloc((size_t)768 * 16384 * 2);
  bf16_t* F = (bf16_t*)alloc((size_t)2 * 384 * 384 * 128 * 2);
  float* part = (float*)alloc((size_t)2 * 512 * 128 * 2 * 4);
  float* ssb = (float*)alloc((size_t)2 * 128 * 2 * 4);

  k_linear<<<dim3(768, 2), 128, 0, stream>>>(h, Wi, bi, Wj, bj, ui_b, vj_b);
  k_wt<<<dim3(128, 4, 4), 256, 0, stream>>>(Wbl, Wt);
  k_wc<<<(147456 + 255) / 256, 256, 0, stream>>>(mw, Wc);
  k_wo<<<64, 256, 0, stream>>>(ow, Wo);
  k_tgemm<<<dim3(12, 256), 256, 0, stream>>>(ui_b, Wt, T);
  k_feat<<<768, 256, 0, stream>>>(T, vj_b, F);
  k_stats1<<<dim3(512, 2), 256, 0, stream>>>(F, part);
  k_stats2<<<1, 256, 0, stream>>>(part, gamma, beta, ssb);
  k_conv<<<dim3(6, 384, 2), 256, 0, stream>>>(F, ssb, Wc, Wo, ob, out);
}

// Round 2
// 323.328 us; speedup vs baseline: 1.8456x; 1.8456x over previous
//
#include <hip/hip_runtime.h>
#include <hip/hip_bf16.h>
#include <stdint.h>

typedef __bf16 bf16_t;
typedef __bf16 bf16x8 __attribute__((ext_vector_type(8)));
typedef float  f32x4  __attribute__((ext_vector_type(4)));

#define MFMA(a, b, c) __builtin_amdgcn_mfma_f32_16x16x32_bf16((a), (b), (c), 0, 0, 0)

__device__ __forceinline__ void gload_lds16(const void* g, void* l) {
  __builtin_amdgcn_global_load_lds(
      (const __attribute__((address_space(1))) unsigned int*)(g),
      (__attribute__((address_space(3))) unsigned int*)(l), 16, 0, 0);
}

// ---------------------------------------------------------------- K1: linears
__global__ __launch_bounds__(128) void k_linear(
    const float* __restrict__ h, const float* __restrict__ Wi,
    const float* __restrict__ bi, const float* __restrict__ Wj,
    const float* __restrict__ bj, bf16_t* __restrict__ ui,
    bf16_t* __restrict__ vj) {
  int bl = blockIdx.x;
  int which = blockIdx.y;
  const float* W = which ? Wj : Wi;
  const float* bias = which ? bj : bi;
  bf16_t* out = which ? vj : ui;
  __shared__ float hrow[1024];
  for (int i = threadIdx.x; i < 1024; i += 128) hrow[i] = h[bl * 1024 + i];
  __syncthreads();
  int p = threadIdx.x;
  const float* w = W + (size_t)p * 1024;
  float acc = bias[p];
  for (int i = 0; i < 1024; i += 4) {
    f32x4 wv = *(const f32x4*)(w + i);
    acc += hrow[i] * wv[0] + hrow[i + 1] * wv[1] + hrow[i + 2] * wv[2] +
           hrow[i + 3] * wv[3];
  }
  out[bl * 128 + p] = (bf16_t)acc;
}

// ------------------------------------------------- K2a: W[i][j][k]->Wt[k][j][i]
__global__ __launch_bounds__(256) void k_wt(const float* __restrict__ W,
                                            bf16_t* __restrict__ Wt) {
  int j = blockIdx.x;
  int i0 = blockIdx.y * 32, k0 = blockIdx.z * 32;
  __shared__ float tile[32][33];
  int tx = threadIdx.x & 31, ty = threadIdx.x >> 5;  // ty 0..7
#pragma unroll
  for (int r = 0; r < 4; r++) {
    int ii = ty + r * 8;
    tile[ii][tx] = W[(size_t)(i0 + ii) * 16384 + j * 128 + (k0 + tx)];
  }
  __syncthreads();
#pragma unroll
  for (int r = 0; r < 4; r++) {
    int kk = ty + r * 8;
    Wt[(size_t)(k0 + kk) * 16384 + j * 128 + (i0 + tx)] = (bf16_t)tile[tx][kk];
  }
}

// ------------------------------- K2b: mix_w[oc][ic][tap] -> Wc[tap][oc][ic] bf16
__global__ __launch_bounds__(256) void k_wc(const float* __restrict__ mw,
                                            bf16_t* __restrict__ Wc) {
  int idx = blockIdx.x * 256 + threadIdx.x;
  if (idx < 147456) {
    int ic = idx & 127, oc = (idx >> 7) & 127, tap = idx >> 14;
    Wc[idx] = (bf16_t)mw[oc * 1152 + ic * 9 + tap];
  }
}

// --------------------------------------------- K2c: out_w -> bf16
__global__ __launch_bounds__(256) void k_wo(const float* __restrict__ ow,
                                            bf16_t* __restrict__ Wo) {
  int idx = blockIdx.x * 256 + threadIdx.x;
  if (idx < 16384) Wo[idx] = (bf16_t)ow[idx];
}

// ------------------- K3: t[bl][k*128+j] = sum_i ui[bl][i] * Wt[k][j][i]  (GEMM)
__global__ __launch_bounds__(256) void k_tgemm(const bf16_t* __restrict__ A,
                                               const bf16_t* __restrict__ Bt,
                                               bf16_t* __restrict__ T) {
  int m0 = blockIdx.x * 64;  // bl
  int n0 = blockIdx.y * 64;  // (k,j)
  __shared__ bf16_t Al[64][136], Bl[64][136];
  for (int c = threadIdx.x; c < 64 * 16; c += 256) {
    int row = c >> 4, col = (c & 15) * 8;
    *(uint4*)&Al[row][col] = *(const uint4*)&A[(size_t)(m0 + row) * 128 + col];
    *(uint4*)&Bl[row][col] = *(const uint4*)&Bt[(size_t)(n0 + row) * 128 + col];
  }
  __syncthreads();
  int w = threadIdx.x >> 6, ln = threadIdx.x & 63;
  int wr = (w >> 1) * 32, wc = (w & 1) * 32;
  int lr = ln & 15, hi8 = (ln >> 4) * 8, rb = (ln >> 4) * 4;
  f32x4 acc[2][2] = {};
#pragma unroll
  for (int kc = 0; kc < 128; kc += 32) {
    bf16x8 a0 = *(bf16x8*)&Al[wr + lr][kc + hi8];
    bf16x8 a1 = *(bf16x8*)&Al[wr + 16 + lr][kc + hi8];
    bf16x8 b0 = *(bf16x8*)&Bl[wc + lr][kc + hi8];
    bf16x8 b1 = *(bf16x8*)&Bl[wc + 16 + lr][kc + hi8];
    acc[0][0] = MFMA(a0, b0, acc[0][0]);
    acc[0][1] = MFMA(a0, b1, acc[0][1]);
    acc[1][0] = MFMA(a1, b0, acc[1][0]);
    acc[1][1] = MFMA(a1, b1, acc[1][1]);
  }
#pragma unroll
  for (int fm = 0; fm < 2; fm++)
#pragma unroll
    for (int fn = 0; fn < 2; fn++) {
      int col = n0 + wc + fn * 16 + lr;
#pragma unroll
      for (int r = 0; r < 4; r++) {
        int row = m0 + wr + fm * 16 + rb + r;
        T[(size_t)row * 16384 + col] = (bf16_t)acc[fm][fn][r];
      }
    }
}

// ------- K4: feat[b][l][m][k] = sum_j t[bl][k][j] * vj[b][m][j]  (per-l GEMMs)
__global__ __launch_bounds__(256) void k_feat(const bf16_t* __restrict__ T,
                                              const bf16_t* __restrict__ Vb,
                                              bf16_t* __restrict__ F) {
  int bl = blockIdx.x;
  int b = bl / 384;
  __shared__ bf16_t Tl[128][136];
  __shared__ bf16_t Vm[64][136];
  const bf16_t* tsrc = T + (size_t)bl * 16384;
  for (int c = threadIdx.x; c < 128 * 16; c += 256) {
    int row = c >> 4, col = (c & 15) * 8;
    *(uint4*)&Tl[row][col] = *(const uint4*)&tsrc[row * 128 + col];
  }
  int w = threadIdx.x >> 6, ln = threadIdx.x & 63;
  int wr = (w >> 1) * 64, wc = (w & 1) * 32;
  int lr = ln & 15, hi8 = (ln >> 4) * 8, rb = (ln >> 4) * 4;
  size_t base = (size_t)bl * 384 * 128;
  for (int mt = 0; mt < 6; mt++) {
    __syncthreads();
    for (int c = threadIdx.x; c < 64 * 16; c += 256) {
      int row = c >> 4, col = (c & 15) * 8;
      *(uint4*)&Vm[row][col] =
          *(const uint4*)&Vb[(size_t)(b * 384 + mt * 64 + row) * 128 + col];
    }
    __syncthreads();
    f32x4 acc[4][2] = {};
#pragma unroll
    for (int kc = 0; kc < 128; kc += 32) {
      bf16x8 b0 = *(bf16x8*)&Vm[wc + lr][kc + hi8];
      bf16x8 b1 = *(bf16x8*)&Vm[wc + 16 + lr][kc + hi8];
#pragma unroll
      for (int fm = 0; fm < 4; fm++) {
        bf16x8 av = *(bf16x8*)&Tl[wr + fm * 16 + lr][kc + hi8];
        acc[fm][0] = MFMA(av, b0, acc[fm][0]);
        acc[fm][1] = MFMA(av, b1, acc[fm][1]);
      }
    }
    union {
      bf16_t h[4];
      uint2 u;
    } pk;
#pragma unroll
    for (int fm = 0; fm < 4; fm++)
#pragma unroll
      for (int fn = 0; fn < 2; fn++) {
        int m = mt * 64 + wc + fn * 16 + lr;
        int kb = wr + fm * 16 + rb;
#pragma unroll
        for (int r = 0; r < 4; r++) pk.h[r] = (bf16_t)acc[fm][fn][r];
        *(uint2*)&F[base + (size_t)m * 128 + kb] = pk.u;
      }
  }
}

// --------------------------- K5a: partial per-(b,k) sum/sumsq over pixel chunks
__global__ __launch_bounds__(256) void k_stats1(const bf16_t* __restrict__ F,
                                                float* __restrict__ part) {
  int b = blockIdx.y, ch = blockIdx.x;  // 512 chunks of 288 pixels
  int k = threadIdx.x & 127, half = threadIdx.x >> 7;
  size_t base = ((size_t)b * 147456 + ch * 288 + half * 144) * 128 + k;
  float s = 0.f, q = 0.f;
  for (int p = 0; p < 144; p++) {
    float v = (float)F[base + (size_t)p * 128];
    s += v;
    q += v * v;
  }
  __shared__ float red[512];
  red[threadIdx.x] = s;
  red[256 + threadIdx.x] = q;
  __syncthreads();
  if (half == 0) {
    part[(((size_t)b * 512 + ch) * 128 + k) * 2] = red[k] + red[128 + k];
    part[(((size_t)b * 512 + ch) * 128 + k) * 2 + 1] =
        red[256 + k] + red[384 + k];
  }
}

// ----------------------------------------- K5b: finalize scale/shift per (b,k)
__global__ __launch_bounds__(256) void k_stats2(const float* __restrict__ part,
                                                const float* __restrict__ gamma,
                                                const float* __restrict__ beta,
                                                float* __restrict__ ss) {
  int t = threadIdx.x;
  int b = t >> 7, k = t & 127;
  float s = 0.f, q = 0.f;
  for (int c = 0; c < 512; c++) {
    s += part[(((size_t)b * 512 + c) * 128 + k) * 2];
    q += part[(((size_t)b * 512 + c) * 128 + k) * 2 + 1];
  }
  const float inv = 1.0f / 147456.0f;
  float mean = s * inv;
  float var = q * inv - mean * mean;
  float sc = gamma[k] * rsqrtf(var + 1e-5f);
  ss[(b * 128 + k) * 2] = sc;
  ss[(b * 128 + k) * 2 + 1] = beta[k] - mean * sc;
}

// --- K7: fused norm+relu -> conv3x3 (implicit GEMM) -> relu -> conv1x1 + bias
// Tap-major: B slab [66 px][128 ic] staged once per dy (vectorized norm+relu);
// A slab = full tap [128 oc][128 ic] via global_load_lds w/ XOR-swizzled source.
// LDS 51.7 KB -> 3 blocks/CU.
__global__ __launch_bounds__(256) void k_conv(
    const bf16_t* __restrict__ F, const float* __restrict__ ss,
    const bf16_t* __restrict__ Wc, const bf16_t* __restrict__ Wo,
    const float* __restrict__ outb, float* __restrict__ out) {
  int xt = blockIdx.x, y = blockIdx.y, b = blockIdx.z;
  int x0 = xt * 64;

  __shared__ __align__(16) char sm[51744];
  // region0 [0,32768): A tap slab (swizzled); later Mx[64][136]
  // region1 [32768,50720): Bsl[66][136]; later Wos[128][40]
  // [50720,51744): ssc/ssh
  bf16_t (*Bsl)[136] = (bf16_t(*)[136])(sm + 32768);
  bf16_t (*Wos)[40] = (bf16_t(*)[40])(sm + 32768);
  bf16_t (*Mx)[136] = (bf16_t(*)[136])(sm);
  float* ssc = (float*)(sm + 50720);
  float* ssh = ssc + 128;

  if (threadIdx.x < 128) {
    ssc[threadIdx.x] = ss[(b * 128 + threadIdx.x) * 2];
    ssh[threadIdx.x] = ss[(b * 128 + threadIdx.x) * 2 + 1];
  }

  int w = threadIdx.x >> 6, ln = threadIdx.x & 63;
  int wr = (w >> 1) * 64, wc4 = (w & 1) * 32;
  int lr = ln & 15, hi8 = (ln >> 4) * 8, rb = (ln >> 4) * 4;
  int hi16 = hi8 * 2;            // column byte offset of the 8-elem group
  int mswz = (lr & 7) << 4;      // per-thread XOR swizzle mask for A reads
  int w4 = w * 8192;

  f32x4 acc[4][2] = {};
  for (int dy = 0; dy < 3; dy++) {
    int yy = y + dy - 1;
    bool yok = (yy >= 0 && yy < 384);
    __syncthreads();  // prior reads of Bsl/Abuf complete
    // ---- stage B slab [66][128] with norm+relu, zero-padded
    const bf16_t* Frow = F + (size_t)(b * 384 + yy) * 384 * 128;
    for (int idx = threadIdx.x; idx < 66 * 16; idx += 256) {
      int px = idx >> 4, c8 = (idx & 15) << 3;
      int xx = x0 - 1 + px;
      bf16x8 o;
      if (yok && xx >= 0 && xx < 384) {
        bf16x8 f = *(const bf16x8*)&Frow[(size_t)xx * 128 + c8];
#pragma unroll
        for (int e = 0; e < 8; e++) {
          float v = (float)f[e] * ssc[c8 + e] + ssh[c8 + e];
          o[e] = (bf16_t)(v > 0.f ? v : 0.f);
        }
      } else {
#pragma unroll
        for (int e = 0; e < 8; e++) o[e] = (bf16_t)0.f;
      }
      *(bf16x8*)&Bsl[px][c8] = o;
    }
    for (int dx = 0; dx < 3; dx++) {
      // ---- stage A tap slab (32 KB) via global_load_lds, swizzled source
      const char* WcTap = (const char*)Wc + (size_t)(dy * 3 + dx) * 32768;
#pragma unroll
      for (int i = 0; i < 8; i++) {
        int q = w4 + i * 1024 + ln * 16;
        int p = q ^ ((q >> 4) & 0x70);
        gload_lds16(WcTap + p, sm + w4 + i * 1024);
      }
      __syncthreads();  // drains vmcnt+lgkm: A and B ready
#pragma unroll
      for (int kc = 0; kc < 4; kc++) {
        bf16x8 b0 = *(bf16x8*)&Bsl[wc4 + lr + dx][kc * 32 + hi8];
        bf16x8 b1 = *(bf16x8*)&Bsl[wc4 + 16 + lr + dx][kc * 32 + hi8];
        int colb = (kc * 64 + hi16) ^ mswz;
#pragma unroll
        for (int fm = 0; fm < 4; fm++) {
          bf16x8 av = *(const bf16x8*)(sm + (wr + fm * 16 + lr) * 256 + colb);
          acc[fm][0] = MFMA(av, b0, acc[fm][0]);
          acc[fm][1] = MFMA(av, b1, acc[fm][1]);
        }
      }
      if (dx < 2) __syncthreads();  // A reads done before next tap overwrite
    }
  }
  // ---- epilogue: relu(mix) -> Mx (overlay on A region), then 1x1 GEMM + bias
  __syncthreads();
  union {
    bf16_t h[4];
    uint2 u;
  } pk;
#pragma unroll
  for (int fm = 0; fm < 4; fm++)
#pragma unroll
    for (int fn = 0; fn < 2; fn++) {
      int px = wc4 + fn * 16 + lr;
      int mcb = wr + fm * 16 + rb;
#pragma unroll
      for (int r = 0; r < 4; r++) {
        float v = acc[fm][fn][r];
        pk.h[r] = (bf16_t)(v > 0.f ? v : 0.f);
      }
      *(uint2*)&Mx[px][mcb] = pk.u;
    }
  f32x4 acc2[4][2] = {};
#pragma unroll 1
  for (int kc = 0; kc < 4; kc++) {
    __syncthreads();  // Mx writes visible (kc==0); Wos reads done (kc>0)
    for (int idx = threadIdx.x; idx < 128 * 4; idx += 256) {
      int oc = idx >> 2, c8 = (idx & 3) << 3;
      *(bf16x8*)&Wos[oc][c8] = *(const bf16x8*)&Wo[oc * 128 + kc * 32 + c8];
    }
    __syncthreads();
    bf16x8 b0 = *(bf16x8*)&Mx[wc4 + lr][kc * 32 + hi8];
    bf16x8 b1 = *(bf16x8*)&Mx[wc4 + 16 + lr][kc * 32 + hi8];
#pragma unroll
    for (int fm = 0; fm < 4; fm++) {
      bf16x8 av = *(bf16x8*)&Wos[wr + fm * 16 + lr][hi8];
      acc2[fm][0] = MFMA(av, b0, acc2[fm][0]);
      acc2[fm][1] = MFMA(av, b1, acc2[fm][1]);
    }
  }
#pragma unroll
  for (int fm = 0; fm < 4; fm++)
#pragma unroll
    for (int fn = 0; fn < 2; fn++) {
      int x = x0 + wc4 + fn * 16 + lr;
#pragma unroll
      for (int r = 0; r < 4; r++) {
        int oc2 = wr + fm * 16 + rb + r;
        out[((size_t)(b * 128 + oc2) * 384 + y) * 384 + x] =
            acc2[fm][fn][r] + outb[oc2];
      }
    }
}

extern "C" void kernel_launch(void* const* d_in, const int* in_sizes, int n_in,
                              void* d_out, int out_size, void* d_ws,
                              size_t ws_size, hipStream_t stream) {
  const float* h = (const float*)d_in[0];
  const float* Wi = (const float*)d_in[1];
  const float* bi = (const float*)d_in[2];
  const float* Wj = (const float*)d_in[3];
  const float* bj = (const float*)d_in[4];
  const float* Wbl = (const float*)d_in[5];
  const float* gamma = (const float*)d_in[6];
  const float* beta = (const float*)d_in[7];
  const float* mw = (const float*)d_in[8];
  const float* ow = (const float*)d_in[9];
  const float* ob = (const float*)d_in[10];
  float* out = (float*)d_out;

  char* ws = (char*)d_ws;
  size_t off = 0;
  auto alloc = [&](size_t bytes) -> void* {
    void* p = ws + off;
    off = (off + bytes + 255) & ~(size_t)255;
    return p;
  };
  bf16_t* ui_b = (bf16_t*)alloc(768 * 128 * 2);
  bf16_t* vj_b = (bf16_t*)alloc(768 * 128 * 2);
  bf16_t* Wt = (bf16_t*)alloc((size_t)2097152 * 2);
  bf16_t* Wc = (bf16_t*)alloc((size_t)147456 * 2);
  bf16_t* Wo = (bf16_t*)alloc((size_t)16384 * 2);
  bf16_t* T = (bf16_t*)alloc((size_t)768 * 16384 * 2);
  bf16_t* F = (bf16_t*)alloc((size_t)2 * 384 * 384 * 128 * 2);
  float* part = (float*)alloc((size_t)2 * 512 * 128 * 2 * 4);
  float* ssb = (float*)alloc((size_t)2 * 128 * 2 * 4);

  k_linear<<<dim3(768, 2), 128, 0, stream>>>(h, Wi, bi, Wj, bj, ui_b, vj_b);
  k_wt<<<dim3(128, 4, 4), 256, 0, stream>>>(Wbl, Wt);
  k_wc<<<(147456 + 255) / 256, 256, 0, stream>>>(mw, Wc);
  k_wo<<<64, 256, 0, stream>>>(ow, Wo);
  k_tgemm<<<dim3(12, 256), 256, 0, stream>>>(ui_b, Wt, T);
  k_feat<<<768, 256, 0, stream>>>(T, vj_b, F);
  k_stats1<<<dim3(512, 2), 256, 0, stream>>>(F, part);
  k_stats2<<<1, 256, 0, stream>>>(part, gamma, beta, ssb);
  k_conv<<<dim3(6, 384, 2), 256, 0, stream>>>(F, ssb, Wc, Wo, ob, out);
}

// Round 3
// 275.913 us; speedup vs baseline: 2.1628x; 1.1719x over previous
//
#include <hip/hip_runtime.h>
#include <hip/hip_bf16.h>
#include <stdint.h>

typedef __bf16 bf16_t;
typedef __bf16 bf16x8 __attribute__((ext_vector_type(8)));
typedef float  f32x4  __attribute__((ext_vector_type(4)));

#define MFMA(a, b, c) __builtin_amdgcn_mfma_f32_16x16x32_bf16((a), (b), (c), 0, 0, 0)

__device__ __forceinline__ void gload_lds16(const void* g, void* l) {
  __builtin_amdgcn_global_load_lds(
      (const __attribute__((address_space(1))) unsigned int*)(g),
      (__attribute__((address_space(3))) unsigned int*)(l), 16, 0, 0);
}

// ---------------------------------------------------------------- K1: linears
__global__ __launch_bounds__(128) void k_linear(
    const float* __restrict__ h, const float* __restrict__ Wi,
    const float* __restrict__ bi, const float* __restrict__ Wj,
    const float* __restrict__ bj, bf16_t* __restrict__ ui,
    bf16_t* __restrict__ vj) {
  int bl = blockIdx.x;
  int which = blockIdx.y;
  const float* W = which ? Wj : Wi;
  const float* bias = which ? bj : bi;
  bf16_t* out = which ? vj : ui;
  __shared__ float hrow[1024];
  for (int i = threadIdx.x; i < 1024; i += 128) hrow[i] = h[bl * 1024 + i];
  __syncthreads();
  int p = threadIdx.x;
  const float* w = W + (size_t)p * 1024;
  float acc = bias[p];
  for (int i = 0; i < 1024; i += 4) {
    f32x4 wv = *(const f32x4*)(w + i);
    acc += hrow[i] * wv[0] + hrow[i + 1] * wv[1] + hrow[i + 2] * wv[2] +
           hrow[i + 3] * wv[3];
  }
  out[bl * 128 + p] = (bf16_t)acc;
}

// ------------------------------------------------- K2a: W[i][j][k]->Wt[k][j][i]
__global__ __launch_bounds__(256) void k_wt(const float* __restrict__ W,
                                            bf16_t* __restrict__ Wt) {
  int j = blockIdx.x;
  int i0 = blockIdx.y * 32, k0 = blockIdx.z * 32;
  __shared__ float tile[32][33];
  int tx = threadIdx.x & 31, ty = threadIdx.x >> 5;  // ty 0..7
#pragma unroll
  for (int r = 0; r < 4; r++) {
    int ii = ty + r * 8;
    tile[ii][tx] = W[(size_t)(i0 + ii) * 16384 + j * 128 + (k0 + tx)];
  }
  __syncthreads();
#pragma unroll
  for (int r = 0; r < 4; r++) {
    int kk = ty + r * 8;
    Wt[(size_t)(k0 + kk) * 16384 + j * 128 + (i0 + tx)] = (bf16_t)tile[tx][kk];
  }
}

// -------- K2b: mix_w[oc][ic][tap] -> Wc2 in MFMA-fragment order
// Wc2[tap][wrh][kc][fm][ln][e]: oc=wrh*64+fm*16+(ln&15), ic=kc*32+(ln>>4)*8+e
__global__ __launch_bounds__(256) void k_wc(const float* __restrict__ mw,
                                            bf16_t* __restrict__ Wc2) {
  int idx = blockIdx.x * 256 + threadIdx.x;
  if (idx < 147456) {
    int e = idx & 7, ln = (idx >> 3) & 63, fm = (idx >> 9) & 3;
    int kc = (idx >> 11) & 3, wrh = (idx >> 13) & 1, tap = idx >> 14;
    int oc = wrh * 64 + fm * 16 + (ln & 15);
    int ic = kc * 32 + (ln >> 4) * 8 + e;
    Wc2[idx] = (bf16_t)mw[oc * 1152 + ic * 9 + tap];
  }
}

// -------- K2c: out_w -> Wo2 in MFMA-fragment order [wrh][kc][fm][ln][e]
__global__ __launch_bounds__(256) void k_wo(const float* __restrict__ ow,
                                            bf16_t* __restrict__ Wo2) {
  int idx = blockIdx.x * 256 + threadIdx.x;
  if (idx < 16384) {
    int e = idx & 7, ln = (idx >> 3) & 63, fm = (idx >> 9) & 3;
    int kc = (idx >> 11) & 3, wrh = (idx >> 13) & 1;
    int oc2 = wrh * 64 + fm * 16 + (ln & 15);
    int mc = kc * 32 + (ln >> 4) * 8 + e;
    Wo2[idx] = (bf16_t)ow[oc2 * 128 + mc];
  }
}

// ------------------- K3: t[bl][k*128+j] = sum_i ui[bl][i] * Wt[k][j][i]  (GEMM)
__global__ __launch_bounds__(256) void k_tgemm(const bf16_t* __restrict__ A,
                                               const bf16_t* __restrict__ Bt,
                                               bf16_t* __restrict__ T) {
  int m0 = blockIdx.x * 64;  // bl
  int n0 = blockIdx.y * 64;  // (k,j)
  __shared__ bf16_t Al[64][136], Bl[64][136];
  for (int c = threadIdx.x; c < 64 * 16; c += 256) {
    int row = c >> 4, col = (c & 15) * 8;
    *(uint4*)&Al[row][col] = *(const uint4*)&A[(size_t)(m0 + row) * 128 + col];
    *(uint4*)&Bl[row][col] = *(const uint4*)&Bt[(size_t)(n0 + row) * 128 + col];
  }
  __syncthreads();
  int w = threadIdx.x >> 6, ln = threadIdx.x & 63;
  int wr = (w >> 1) * 32, wc = (w & 1) * 32;
  int lr = ln & 15, hi8 = (ln >> 4) * 8, rb = (ln >> 4) * 4;
  f32x4 acc[2][2] = {};
#pragma unroll
  for (int kc = 0; kc < 128; kc += 32) {
    bf16x8 a0 = *(bf16x8*)&Al[wr + lr][kc + hi8];
    bf16x8 a1 = *(bf16x8*)&Al[wr + 16 + lr][kc + hi8];
    bf16x8 b0 = *(bf16x8*)&Bl[wc + lr][kc + hi8];
    bf16x8 b1 = *(bf16x8*)&Bl[wc + 16 + lr][kc + hi8];
    acc[0][0] = MFMA(a0, b0, acc[0][0]);
    acc[0][1] = MFMA(a0, b1, acc[0][1]);
    acc[1][0] = MFMA(a1, b0, acc[1][0]);
    acc[1][1] = MFMA(a1, b1, acc[1][1]);
  }
#pragma unroll
  for (int fm = 0; fm < 2; fm++)
#pragma unroll
    for (int fn = 0; fn < 2; fn++) {
      int col = n0 + wc + fn * 16 + lr;
#pragma unroll
      for (int r = 0; r < 4; r++) {
        int row = m0 + wr + fm * 16 + rb + r;
        T[(size_t)row * 16384 + col] = (bf16_t)acc[fm][fn][r];
      }
    }
}

// ------- K4: feat[b][l][m][k] = sum_j t[bl][k][j] * vj[b][m][j]
// LDS-bounce for coalesced F writes; fused deterministic norm partial sums.
__global__ __launch_bounds__(256) void k_feat(const bf16_t* __restrict__ T,
                                              const bf16_t* __restrict__ Vb,
                                              bf16_t* __restrict__ F,
                                              float* __restrict__ part) {
  int bl = blockIdx.x;
  int b = bl / 384;
  __shared__ __align__(16) char sm[69632];
  bf16_t (*Tl)[136] = (bf16_t(*)[136])(sm);            // 34816
  bf16_t (*Vm)[136] = (bf16_t(*)[136])(sm + 34816);    // 17408
  bf16_t (*Fb)[136] = (bf16_t(*)[136])(sm + 52224);    // 17408
  float* rs = (float*)(sm);                            // overlay after loop
  float* rq = (float*)(sm + 8192);
  const bf16_t* tsrc = T + (size_t)bl * 16384;
  for (int c = threadIdx.x; c < 128 * 16; c += 256) {
    int row = c >> 4, col = (c & 15) * 8;
    *(uint4*)&Tl[row][col] = *(const uint4*)&tsrc[row * 128 + col];
  }
  int w = threadIdx.x >> 6, ln = threadIdx.x & 63;
  int wr = (w >> 1) * 64, wc = (w & 1) * 32;
  int lr = ln & 15, hi8 = (ln >> 4) * 8, rb = (ln >> 4) * 4;
  size_t base = (size_t)bl * 384 * 128;
  float s8[8] = {}, q8[8] = {};
  int col8 = threadIdx.x & 15;
  for (int mt = 0; mt < 6; mt++) {
    __syncthreads();
    for (int c = threadIdx.x; c < 64 * 16; c += 256) {
      int row = c >> 4, col = (c & 15) * 8;
      *(uint4*)&Vm[row][col] =
          *(const uint4*)&Vb[(size_t)(b * 384 + mt * 64 + row) * 128 + col];
    }
    __syncthreads();
    f32x4 acc[4][2] = {};
#pragma unroll
    for (int kc = 0; kc < 128; kc += 32) {
      bf16x8 b0 = *(bf16x8*)&Vm[wc + lr][kc + hi8];
      bf16x8 b1 = *(bf16x8*)&Vm[wc + 16 + lr][kc + hi8];
#pragma unroll
      for (int fm = 0; fm < 4; fm++) {
        bf16x8 av = *(bf16x8*)&Tl[wr + fm * 16 + lr][kc + hi8];
        acc[fm][0] = MFMA(av, b0, acc[fm][0]);
        acc[fm][1] = MFMA(av, b1, acc[fm][1]);
      }
    }
    union {
      bf16_t h[4];
      uint2 u;
    } pk;
#pragma unroll
    for (int fm = 0; fm < 4; fm++)
#pragma unroll
      for (int fn = 0; fn < 2; fn++) {
        int m = wc + fn * 16 + lr;
        int kb = wr + fm * 16 + rb;
#pragma unroll
        for (int r = 0; r < 4; r++) pk.h[r] = (bf16_t)acc[fm][fn][r];
        *(uint2*)&Fb[m][kb] = pk.u;
      }
    __syncthreads();
    // coalesced copy-out + stats accumulation
    for (int c = threadIdx.x; c < 64 * 16; c += 256) {
      int row = c >> 4;
      uint4 v = *(uint4*)&Fb[row][col8 * 8];
      *(uint4*)&F[base + (size_t)(mt * 64 + row) * 128 + col8 * 8] = v;
      const bf16_t* hp = (const bf16_t*)&v;
#pragma unroll
      for (int e = 0; e < 8; e++) {
        float f = (float)hp[e];
        s8[e] += f;
        q8[e] += f * f;
      }
    }
  }
  // deterministic block reduction over the 16 row-groups
  int sub = threadIdx.x >> 4;
#pragma unroll
  for (int e = 0; e < 8; e++) {
    rs[(sub * 16 + col8) * 8 + e] = s8[e];
    rq[(sub * 16 + col8) * 8 + e] = q8[e];
  }
  __syncthreads();
  if (threadIdx.x < 128) {
    int k = threadIdx.x, kg = k >> 3, e = k & 7;
    float S = 0.f, Q = 0.f;
#pragma unroll
    for (int s = 0; s < 16; s++) {
      S += rs[(s * 16 + kg) * 8 + e];
      Q += rq[(s * 16 + kg) * 8 + e];
    }
    part[(size_t)bl * 256 + k] = S;
    part[(size_t)bl * 256 + 128 + k] = Q;
  }
}

// ----------------------------------------- K5: finalize scale/shift per (b,k)
__global__ __launch_bounds__(64) void k_stats2(const float* __restrict__ part,
                                               const float* __restrict__ gamma,
                                               const float* __restrict__ beta,
                                               float* __restrict__ ss) {
  int k = blockIdx.x, b = blockIdx.y, t = threadIdx.x;
  float S = 0.f, Q = 0.f;
  for (int l = t; l < 384; l += 64) {
    S += part[(size_t)(b * 384 + l) * 256 + k];
    Q += part[(size_t)(b * 384 + l) * 256 + 128 + k];
  }
#pragma unroll
  for (int o = 32; o; o >>= 1) {
    S += __shfl_down(S, o, 64);
    Q += __shfl_down(Q, o, 64);
  }
  if (t == 0) {
    const float inv = 1.0f / 147456.0f;
    float mean = S * inv;
    float var = Q * inv - mean * mean;
    float sc = gamma[k] * rsqrtf(var + 1e-5f);
    ss[(b * 128 + k) * 2] = sc;
    ss[(b * 128 + k) * 2 + 1] = beta[k] - mean * sc;
  }
}

// --- K7: fused norm+relu -> conv3x3 (implicit GEMM) -> relu -> conv1x1 + bias
// 128oc x 128px tile; A in fragment order (conflict-free contiguous ds_read);
// linear global_load_lds staging; XCD-swizzled block order for F L2 locality.
__global__ __launch_bounds__(256, 2) void k_conv(
    const bf16_t* __restrict__ F, const float* __restrict__ ss,
    const bf16_t* __restrict__ Wc2, const bf16_t* __restrict__ Wo2,
    const float* __restrict__ outb, float* __restrict__ out) {
  int orig = blockIdx.x;
  int wg = (orig & 7) * 288 + (orig >> 3);  // 2304 % 8 == 0: bijective
  int xt = wg % 3;
  int t1 = wg / 3;
  int b = t1 / 384;
  int y = t1 - b * 384;
  int x0 = xt * 128;

  __shared__ __align__(16) char sm[69152];
  // [0,32768): A tap slab (fragment order); epilogue: Wo2
  // [32768,68128): Bsl[130][136]; epilogue: Mx[128][136]
  // [68128,69152): ssc/ssh
  bf16_t (*Bsl)[136] = (bf16_t(*)[136])(sm + 32768);
  bf16_t (*Mx)[136] = (bf16_t(*)[136])(sm + 32768);
  float* ssc = (float*)(sm + 68128);
  float* ssh = ssc + 128;

  if (threadIdx.x < 128) {
    ssc[threadIdx.x] = ss[(b * 128 + threadIdx.x) * 2];
    ssh[threadIdx.x] = ss[(b * 128 + threadIdx.x) * 2 + 1];
  }

  int w = threadIdx.x >> 6, ln = threadIdx.x & 63;
  int wrh = w >> 1, pxb = (w & 1) * 64;
  int lr = ln & 15, hi8 = (ln >> 4) * 8, rb = (ln >> 4) * 4;
  // per-thread A fragment base (bytes) and Bsl row base
  int abase = wrh * 16384 + ln * 16;
  const char* sA = sm;

  f32x4 acc[4][4] = {};
  for (int dy = 0; dy < 3; dy++) {
    int yy = y + dy - 1;
    bool yok = (yy >= 0 && yy < 384);
    __syncthreads();  // Bsl overwrite safe; (dy=0) ssc ready
    const bf16_t* Frow = F + (size_t)(b * 384 + yy) * 384 * 128;
    for (int idx = threadIdx.x; idx < 130 * 16; idx += 256) {
      int px = idx >> 4, c8 = (idx & 15) << 3;
      int xx = x0 - 1 + px;
      bf16x8 o;
      if (yok && xx >= 0 && xx < 384) {
        bf16x8 f = *(const bf16x8*)&Frow[(size_t)xx * 128 + c8];
#pragma unroll
        for (int e = 0; e < 8; e++) {
          float v = (float)f[e] * ssc[c8 + e] + ssh[c8 + e];
          o[e] = (bf16_t)(v > 0.f ? v : 0.f);
        }
      } else {
#pragma unroll
        for (int e = 0; e < 8; e++) o[e] = (bf16_t)0.f;
      }
      *(bf16x8*)&Bsl[px][c8] = o;
    }
    for (int dx = 0; dx < 3; dx++) {
      if (dx) __syncthreads();  // A reads of prev tap done
      const char* WcTap = (const char*)Wc2 + (size_t)(dy * 3 + dx) * 32768;
#pragma unroll
      for (int i = 0; i < 8; i++) {
        int o4 = w * 8192 + i * 1024 + ln * 16;
        gload_lds16(WcTap + o4, sm + o4);
      }
      __syncthreads();  // drains vmcnt+lgkm: A and B ready
#pragma unroll
      for (int kc = 0; kc < 4; kc++) {
        bf16x8 bv[4];
#pragma unroll
        for (int fn = 0; fn < 4; fn++)
          bv[fn] = *(bf16x8*)&Bsl[pxb + fn * 16 + lr + dx][kc * 32 + hi8];
#pragma unroll
        for (int fm = 0; fm < 4; fm++) {
          bf16x8 av =
              *(const bf16x8*)(sA + abase + kc * 4096 + fm * 1024);
#pragma unroll
          for (int fn = 0; fn < 4; fn++)
            acc[fm][fn] = MFMA(av, bv[fn], acc[fm][fn]);
        }
      }
    }
  }
  // ---- epilogue: stage Wo2 (A region), relu(mix)->Mx (B region), 1x1 + bias
  __syncthreads();  // all MFMA reads done
#pragma unroll
  for (int i = 0; i < 8; i++) {
    int o4 = w * 8192 + i * 1024 + ln * 16;
    gload_lds16((const char*)Wo2 + o4, sm + o4);
  }
  union {
    bf16_t h[4];
    uint2 u;
  } pk;
#pragma unroll
  for (int fm = 0; fm < 4; fm++)
#pragma unroll
    for (int fn = 0; fn < 4; fn++) {
      int px = pxb + fn * 16 + lr;
      int mcb = wrh * 64 + fm * 16 + rb;
#pragma unroll
      for (int r = 0; r < 4; r++) {
        float v = acc[fm][fn][r];
        pk.h[r] = (bf16_t)(v > 0.f ? v : 0.f);
      }
      *(uint2*)&Mx[px][mcb] = pk.u;
    }
  __syncthreads();  // Wo2 + Mx ready
  f32x4 acc2[4][4] = {};
#pragma unroll
  for (int kc = 0; kc < 4; kc++) {
    bf16x8 bv[4];
#pragma unroll
    for (int fn = 0; fn < 4; fn++)
      bv[fn] = *(bf16x8*)&Mx[pxb + fn * 16 + lr][kc * 32 + hi8];
#pragma unroll
    for (int fm = 0; fm < 4; fm++) {
      bf16x8 av = *(const bf16x8*)(sA + abase + kc * 4096 + fm * 1024);
#pragma unroll
      for (int fn = 0; fn < 4; fn++)
        acc2[fm][fn] = MFMA(av, bv[fn], acc2[fm][fn]);
    }
  }
  f32x4 obv[4];
#pragma unroll
  for (int fm = 0; fm < 4; fm++)
    obv[fm] = *(const f32x4*)&outb[wrh * 64 + fm * 16 + rb];
#pragma unroll
  for (int fm = 0; fm < 4; fm++)
#pragma unroll
    for (int fn = 0; fn < 4; fn++) {
      int x = x0 + pxb + fn * 16 + lr;
#pragma unroll
      for (int r = 0; r < 4; r++) {
        int oc2 = wrh * 64 + fm * 16 + rb + r;
        out[((size_t)(b * 128 + oc2) * 384 + y) * 384 + x] =
            acc2[fm][fn][r] + obv[fm][r];
      }
    }
}

extern "C" void kernel_launch(void* const* d_in, const int* in_sizes, int n_in,
                              void* d_out, int out_size, void* d_ws,
                              size_t ws_size, hipStream_t stream) {
  const float* h = (const float*)d_in[0];
  const float* Wi = (const float*)d_in[1];
  const float* bi = (const float*)d_in[2];
  const float* Wj = (const float*)d_in[3];
  const float* bj = (const float*)d_in[4];
  const float* Wbl = (const float*)d_in[5];
  const float* gamma = (const float*)d_in[6];
  const float* beta = (const float*)d_in[7];
  const float* mw = (const float*)d_in[8];
  const float* ow = (const float*)d_in[9];
  const float* ob = (const float*)d_in[10];
  float* out = (float*)d_out;

  char* ws = (char*)d_ws;
  size_t off = 0;
  auto alloc = [&](size_t bytes) -> void* {
    void* p = ws + off;
    off = (off + bytes + 255) & ~(size_t)255;
    return p;
  };
  bf16_t* ui_b = (bf16_t*)alloc(768 * 128 * 2);
  bf16_t* vj_b = (bf16_t*)alloc(768 * 128 * 2);
  bf16_t* Wt = (bf16_t*)alloc((size_t)2097152 * 2);
  bf16_t* Wc2 = (bf16_t*)alloc((size_t)147456 * 2);
  bf16_t* Wo2 = (bf16_t*)alloc((size_t)16384 * 2);
  bf16_t* T = (bf16_t*)alloc((size_t)768 * 16384 * 2);
  bf16_t* F = (bf16_t*)alloc((size_t)2 * 384 * 384 * 128 * 2);
  float* part = (float*)alloc((size_t)768 * 256 * 4);
  float* ssb = (float*)alloc((size_t)2 * 128 * 2 * 4);

  k_linear<<<dim3(768, 2), 128, 0, stream>>>(h, Wi, bi, Wj, bj, ui_b, vj_b);
  k_wt<<<dim3(128, 4, 4), 256, 0, stream>>>(Wbl, Wt);
  k_wc<<<(147456 + 255) / 256, 256, 0, stream>>>(mw, Wc2);
  k_wo<<<64, 256, 0, stream>>>(ow, Wo2);
  k_tgemm<<<dim3(12, 256), 256, 0, stream>>>(ui_b, Wt, T);
  k_feat<<<768, 256, 0, stream>>>(T, vj_b, F, part);
  k_stats2<<<dim3(128, 2), 64, 0, stream>>>(part, gamma, beta, ssb);
  k_conv<<<2304, 256, 0, stream>>>(F, ssb, Wc2, Wo2, ob, out);
}